// Round 1
// baseline (391.148 us; speedup 1.0000x reference)
//
#include <hip/hip_runtime.h>
#include <math.h>

// VectorQuantizer: 131072 rows of D=64, argmin over K=1024 codes,
// gather codebook + histogram -> perplexity.
// Layout: inputs NCHW [32,64,64,64]; flat row = n*4096 + h*64 + w,
// channel c at offset (n<<18) + (c<<12) + hw.

#define NROWS (32 * 64 * 64)   // 131072
#define KCODES 1024
#define DIM 64

// ---- kernel 1: codebook squared norms (match ref: sum(c*c) per code) ----
__global__ __launch_bounds__(256) void vq_cc_kernel(const float* __restrict__ cb,
                                                    float* __restrict__ cc) {
    int k = blockIdx.x * 256 + threadIdx.x;
    if (k < KCODES) {
        const float* c = cb + k * DIM;
        float a0 = 0.f, a1 = 0.f, a2 = 0.f, a3 = 0.f;
        #pragma unroll
        for (int i = 0; i < DIM; i += 4) {
            a0 = fmaf(c[i + 0], c[i + 0], a0);
            a1 = fmaf(c[i + 1], c[i + 1], a1);
            a2 = fmaf(c[i + 2], c[i + 2], a2);
            a3 = fmaf(c[i + 3], c[i + 3], a3);
        }
        cc[k] = (a0 + a1) + (a2 + a3);
    }
}

// ---- kernel 2: main quantization ----
// One thread per row. x row lives in 64 VGPRs; codebook index is
// wave-uniform so codebook reads should lower to scalar (s_load) streams
// that dual-issue with the FMA chain.
__global__ __launch_bounds__(256) void vq_main_kernel(const float* __restrict__ x,
                                                      const float* __restrict__ cb,
                                                      const float* __restrict__ cc,
                                                      float* __restrict__ out,
                                                      unsigned int* __restrict__ counts) {
    int row = blockIdx.x * 256 + threadIdx.x;
    int n  = row >> 12;
    int hw = row & 4095;
    const float* xp = x + ((size_t)n << 18) + hw;

    float xv[DIM];
    #pragma unroll
    for (int c = 0; c < DIM; c++) xv[c] = xp[(size_t)c << 12];

    // ||x||^2 in fp32 (8-accumulator + pairwise combine, numpy-like order;
    // sub-ulp differences get absorbed by the +s quantization at mag ~64)
    float r[8];
    #pragma unroll
    for (int j = 0; j < 8; j++) r[j] = 0.f;
    #pragma unroll
    for (int i = 0; i < DIM; i += 8) {
        #pragma unroll
        for (int j = 0; j < 8; j++) r[j] = fmaf(xv[i + j], xv[i + j], r[j]);
    }
    float s = ((r[0] + r[1]) + (r[2] + r[3])) + ((r[4] + r[5]) + (r[6] + r[7]));

    float dmin = 3.402823466e+38f;
    int   kmin = 0;
    for (int k = 0; k < KCODES; k++) {
        const float* cbk = cb + k * DIM;
        float a0 = 0.f, a1 = 0.f, a2 = 0.f, a3 = 0.f;
        #pragma unroll
        for (int c = 0; c < DIM; c += 4) {
            a0 = fmaf(xv[c + 0], cbk[c + 0], a0);
            a1 = fmaf(xv[c + 1], cbk[c + 1], a1);
            a2 = fmaf(xv[c + 2], cbk[c + 2], a2);
            a3 = fmaf(xv[c + 3], cbk[c + 3], a3);
        }
        float dot = (a0 + a1) + (a2 + a3);
        // match ref association: (s + cc[k]) - 2*dot, fp32 each step
        float d = (s + cc[k]) - 2.0f * dot;
        if (d < dmin) { dmin = d; kmin = k; }   // strict < keeps first index (ties)
    }

    // straight-through value: x + (q - x), fp32 op order mimics reference
    const float* q = cb + kmin * DIM;
    float* op = out + ((size_t)n << 18) + hw;
    #pragma unroll
    for (int c = 0; c < DIM; c++) {
        float xc = xv[c];
        op[(size_t)c << 12] = xc + (q[c] - xc);
    }

    atomicAdd(&counts[kmin], 1u);
}

// ---- kernel 3: perplexity from histogram ----
__global__ __launch_bounds__(1024) void vq_ppl_kernel(const unsigned int* __restrict__ counts,
                                                      float* __restrict__ out) {
    __shared__ float red[16];
    int k = threadIdx.x;
    float p = (float)counts[k] / (float)NROWS;
    float v = p * logf(p + 1e-10f);
    // wave64 reduce
    #pragma unroll
    for (int off = 32; off > 0; off >>= 1) v += __shfl_down(v, off, 64);
    int wave = k >> 6;
    int lane = k & 63;
    if (lane == 0) red[wave] = v;
    __syncthreads();
    if (k == 0) {
        float sum = 0.f;
        #pragma unroll
        for (int w = 0; w < 16; w++) sum += red[w];
        float ppl = expf(-sum);
        out[8388608] = 0.0f;   // loss (eval branch)
        out[8388609] = ppl;    // perplexity
    }
}

extern "C" void kernel_launch(void* const* d_in, const int* in_sizes, int n_in,
                              void* d_out, int out_size, void* d_ws, size_t ws_size,
                              hipStream_t stream) {
    const float* x  = (const float*)d_in[0];
    const float* cb = (const float*)d_in[1];
    float* out = (float*)d_out;

    unsigned int* counts = (unsigned int*)d_ws;                 // 1024 u32
    float*        cc     = (float*)((char*)d_ws + 4096);        // 1024 f32

    hipMemsetAsync(d_ws, 0, 4096, stream);                      // zero histogram
    vq_cc_kernel<<<(KCODES + 255) / 256, 256, 0, stream>>>(cb, cc);
    vq_main_kernel<<<NROWS / 256, 256, 0, stream>>>(x, cb, cc, out, counts);
    vq_ppl_kernel<<<1, 1024, 0, stream>>>(counts, out);
}